// Round 7
// baseline (370.433 us; speedup 1.0000x reference)
//
#include <hip/hip_runtime.h>

typedef __bf16 bf16;
typedef __attribute__((ext_vector_type(8))) __bf16 bf16x8;
typedef __attribute__((ext_vector_type(2))) __bf16 bf16x2;
typedef __attribute__((ext_vector_type(4))) float f32x4;
typedef __attribute__((ext_vector_type(16))) float f32x16;
typedef __attribute__((ext_vector_type(8))) unsigned short ushort8;   // 16B
typedef __attribute__((ext_vector_type(4))) unsigned short ushort4v;  // 8B

__device__ __forceinline__ unsigned short f2bf(float f) {
    union { float f; unsigned int u; } v; v.f = f;
    unsigned int u = v.u;
    return (unsigned short)((u + 0x7fffu + ((u >> 16) & 1u)) >> 16);
}

#if __has_builtin(__builtin_amdgcn_cvt_pk_bf16_f32)
__device__ __forceinline__ unsigned int pk2bf(float a, float b) {
    union { bf16x2 v; unsigned int u; } c;
    c.v = __builtin_amdgcn_cvt_pk_bf16_f32(a, b);
    return c.u;
}
#else
__device__ __forceinline__ unsigned int pk2bf(float a, float b) {
    return (unsigned int)f2bf(a) | ((unsigned int)f2bf(b) << 16);
}
#endif

__device__ __forceinline__ f32x4 mfma16(bf16x8 a, bf16x8 b, f32x4 c) {
    return __builtin_amdgcn_mfma_f32_16x16x32_bf16(a, b, c, 0, 0, 0);
}
__device__ __forceinline__ f32x16 mfma32(bf16x8 a, bf16x8 b, f32x16 c) {
    return __builtin_amdgcn_mfma_f32_32x32x16_bf16(a, b, c, 0, 0, 0);
}

// ---------------- fused fp32 -> bf16 convert ----------------
__global__ void cvt3_f32_bf16(const float* __restrict__ x, const float* __restrict__ wq,
                              const float* __restrict__ wp,
                              unsigned short* __restrict__ xb, unsigned short* __restrict__ wqb,
                              unsigned short* __restrict__ wpb) {
    int i = blockIdx.x * 256 + threadIdx.x;   // float4 index
    const float* in; unsigned short* out; int base;
    if (i < 1572864)      { in = x;  out = xb;  base = i; }
    else if (i < 2015232) { in = wq; out = wqb; base = i - 1572864; }
    else if (i < 2162688) { in = wp; out = wpb; base = i - 2015232; }
    else return;
    float4 f = reinterpret_cast<const float4*>(in)[base];
    union { ushort4v v; unsigned int u[2]; } o;
    o.u[0] = pk2bf(f.x, f.y);
    o.u[1] = pk2bf(f.z, f.w);
    reinterpret_cast<ushort4v*>(out)[base] = o.v;
}

// key permutation for 32x32 S^T C-layout -> PV A-layout:  p: a -> bits (a0,a1,a3,a4,a2)
__device__ __forceinline__ int kperm(int k5) {
    return (k5 & 3) | (((k5 >> 3) & 1) << 2) | (((k5 >> 4) & 1) << 3) | (((k5 >> 2) & 1) << 4);
}

// ---------------- QKV GEMM: [8192x768] x [2304x768]^T, scatter to Q,K,Vt ----------------
// Q pre-scaled by SCALE*log2(e). K rows permuted within 32-groups via kperm (V identity).
__global__ __launch_bounds__(256) void qkv_gemm(const unsigned short* __restrict__ A,
                                                const unsigned short* __restrict__ W,
                                                unsigned short* __restrict__ Qg,
                                                unsigned short* __restrict__ Kg,
                                                unsigned short* __restrict__ Vtg) {
    __shared__ __align__(16) unsigned short As[128 * 40];
    __shared__ __align__(16) unsigned short Bs[128 * 40];
    const int t = threadIdx.x;
    const int w = t >> 6, l = t & 63;
    const int wm = (w >> 1) * 64, wn = (w & 1) * 64;
    const int lr = l & 15, lq = l >> 4;
    const int m0 = blockIdx.y * 128, n0 = blockIdx.x * 128;
    f32x4 acc[4][4] = {};
    for (int k0 = 0; k0 < 768; k0 += 32) {
        __syncthreads();
#pragma unroll
        for (int i = 0; i < 2; ++i) {
            int v = t + i * 256;
            int r = v >> 2, c8 = (v & 3) * 8;
            *reinterpret_cast<ushort8*>(&As[r * 40 + c8]) =
                *reinterpret_cast<const ushort8*>(&A[(m0 + r) * 768 + k0 + c8]);
            *reinterpret_cast<ushort8*>(&Bs[r * 40 + c8]) =
                *reinterpret_cast<const ushort8*>(&W[(n0 + r) * 768 + k0 + c8]);
        }
        __syncthreads();
        bf16x8 af[4], bfr[4];
#pragma unroll
        for (int mt = 0; mt < 4; ++mt)
            af[mt] = *reinterpret_cast<const bf16x8*>(&As[(wm + mt * 16 + lr) * 40 + lq * 8]);
#pragma unroll
        for (int nt = 0; nt < 4; ++nt)
            bfr[nt] = *reinterpret_cast<const bf16x8*>(&Bs[(wn + nt * 16 + lr) * 40 + lq * 8]);
#pragma unroll
        for (int mt = 0; mt < 4; ++mt)
#pragma unroll
            for (int nt = 0; nt < 4; ++nt)
                acc[mt][nt] = mfma16(af[mt], bfr[nt], acc[mt][nt]);
    }
#pragma unroll
    for (int nt = 0; nt < 4; ++nt) {
        int gn = n0 + wn + nt * 16 + lr;
        int tsel = gn / 768, rem = gn - tsel * 768;
        int h = rem / 96, d = rem - h * 96;
#pragma unroll
        for (int mt = 0; mt < 4; ++mt) {
#pragma unroll
            for (int r = 0; r < 4; ++r) {
                int gm = m0 + wm + mt * 16 + lq * 4 + r;
                int b = gm >> 12, n = gm & 4095;
                int bh = b * 8 + h;
                float val = acc[mt][nt][r];
                if (tsel == 0)      Qg[(bh * 4096 + n) * 96 + d] = f2bf(val * 0.14724444f);
                else if (tsel == 1) {
                    int np = (n & ~31) | kperm(n & 31);
                    Kg[(bh * 4096 + np) * 96 + d] = f2bf(val);
                } else              Vtg[(bh * 96 + d) * 4096 + n] = f2bf(val);
            }
        }
    }
}

// ---------------- Flash attention: 32x32 MFMA, 64q x 32k waves, P-in-registers ----------------
// 256 threads = 4 waves (wr: 64 q-rows each, wk: 32 keys). Br=128, Tc=64.
// S^T = K_perm Q^T in 32x32x16; C-regs ARE the PV A-frags (key perm baked into Kg).
// V identity layout -> PV B-frags are plain b128. Row-sum l via ones-B MFMA (layout-exact).
// 2 independent blocks/CU (LDS 27.1 KB, launch_bounds(256,2): 256-reg cap).
__global__ __launch_bounds__(256, 2) void attn_kernel(const unsigned short* __restrict__ Qg,
                                                      const unsigned short* __restrict__ Kg,
                                                      const unsigned short* __restrict__ Vtg,
                                                      unsigned short* __restrict__ Og) {
    __shared__ __align__(16) char lds[27136];
    unsigned short* Qs = (unsigned short*)lds;              // 128x96 (prologue only)
    unsigned short* Ks = (unsigned short*)lds;              // 64x104 (aliases Qs)
    unsigned short* Vs = (unsigned short*)(lds + 13312);    // 96x72
    float*          red = (float*)lds;                      // epilogue reduce

    const int t = threadIdx.x;
    const int w = t >> 6, l = t & 63;
    const int wr = w >> 1, wk = w & 1;
    const int l31 = l & 31, h = l >> 5;
    const int bh = blockIdx.y;
    const int q0 = blockIdx.x * 128;
    const int qbase = bh * 4096 * 96;

    // stage Q tile (1536 ushort8 over 256 threads)
#pragma unroll
    for (int i = 0; i < 6; ++i) {
        int v = t + i * 256;
        int r = v / 12, c8 = (v % 12) * 8;
        *reinterpret_cast<ushort8*>(&Qs[r * 96 + c8]) =
            *reinterpret_cast<const ushort8*>(&Qg[qbase + (q0 + r) * 96 + c8]);
    }
    __syncthreads();
    // hoist Q B-frags: B[k=dim][n=qrow]: lane n=l31, k-half h. 12 frags (2 qn x 6 kq).
    bf16x8 aq[2][6];
#pragma unroll
    for (int qn = 0; qn < 2; ++qn)
#pragma unroll
        for (int kq = 0; kq < 6; ++kq)
            aq[qn][kq] = *reinterpret_cast<const bf16x8*>(
                &Qs[(wr * 64 + qn * 32 + l31) * 96 + kq * 16 + h * 8]);

    bf16x8 ones8;
#pragma unroll
    for (int i = 0; i < 8; ++i) ones8[i] = (__bf16)1.0f;

    f32x16 acc[2][3] = {};   // [qn][dn]  O partial (this wk's 32 keys per iter)
    f32x16 acc_l[2] = {};    // row sums, same C-layout

    for (int kv0 = 0; kv0 < 4096; kv0 += 64) {
        __syncthreads();
        // stage K (64x96, rows pre-permuted in Kg) and Vt (96x64 identity)
#pragma unroll
        for (int j = 0; j < 6; ++j) {
            int v = t + j * 256;
            if (v < 768) {
                int r = v / 12, c8 = (v % 12) * 8;
                *reinterpret_cast<ushort8*>(&Ks[r * 104 + c8]) =
                    *reinterpret_cast<const ushort8*>(&Kg[qbase + (kv0 + r) * 96 + c8]);
            } else {
                int u = v - 768;
                int d = u >> 3, c8v = (u & 7) * 8;
                *reinterpret_cast<ushort8*>(&Vs[d * 72 + c8v]) =
                    *reinterpret_cast<const ushort8*>(&Vtg[(bh * 96 + d) * 4096 + kv0 + c8v]);
            }
        }
        __syncthreads();
        // S^T = K Q^T (32x32x16): A=K rows (positions), B=Q. s[qn]: col=q (l31), row=key-pos.
        f32x16 s[2] = {};
#pragma unroll
        for (int kq = 0; kq < 6; ++kq) {
            bf16x8 bk = *reinterpret_cast<const bf16x8*>(
                &Ks[(wk * 32 + l31) * 104 + kq * 16 + h * 8]);
#pragma unroll
            for (int qn = 0; qn < 2; ++qn)
                s[qn] = mfma32(bk, aq[qn][kq], s[qn]);
        }
        // p = exp2(s); C-reg -> PV A-frag slot map: frag f slot j <- reg (j&3)+8*((j>>2)&1)+4*f
        union PF { unsigned int u[4]; bf16x8 v8; } p[2][2];
#pragma unroll
        for (int qn = 0; qn < 2; ++qn) {
            float e[16];
#pragma unroll
            for (int r = 0; r < 16; ++r) e[r] = __builtin_amdgcn_exp2f(s[qn][r]);
#pragma unroll
            for (int f = 0; f < 2; ++f) {
                p[qn][f].u[0] = pk2bf(e[4 * f + 0], e[4 * f + 1]);
                p[qn][f].u[1] = pk2bf(e[4 * f + 2], e[4 * f + 3]);
                p[qn][f].u[2] = pk2bf(e[8 + 4 * f + 0], e[8 + 4 * f + 1]);
                p[qn][f].u[3] = pk2bf(e[8 + 4 * f + 2], e[8 + 4 * f + 3]);
            }
        }
        // O += P V (32x32x16): B-frag = V[k=key][n=d] straight b128 (identity V)
#pragma unroll
        for (int dn = 0; dn < 3; ++dn) {
#pragma unroll
            for (int f = 0; f < 2; ++f) {
                bf16x8 vb = *reinterpret_cast<const bf16x8*>(
                    &Vs[(dn * 32 + l31) * 72 + wk * 32 + f * 16 + h * 8]);
#pragma unroll
                for (int qn = 0; qn < 2; ++qn)
                    acc[qn][dn] = mfma32(p[qn][f].v8, vb, acc[qn][dn]);
            }
        }
#pragma unroll
        for (int qn = 0; qn < 2; ++qn)
#pragma unroll
            for (int f = 0; f < 2; ++f)
                acc_l[qn] = mfma32(p[qn][f].v8, ones8, acc_l[qn]);
    }

    // ---- cross-wave reduce over wk (4 pass-pairs, stride 36 floats) ----
    const int rbase = (wr * 64 + l) * 36;
#pragma unroll
    for (int ps = 0; ps < 3; ++ps) {
        __syncthreads();
        if (wk == 1) {
#pragma unroll
            for (int c = 0; c < 2; ++c) {
                int c2 = ps * 2 + c, qn = c2 / 3, dn = c2 % 3;
#pragma unroll
                for (int u = 0; u < 4; ++u) {
                    f32x4 tmp;
#pragma unroll
                    for (int j = 0; j < 4; ++j) tmp[j] = acc[qn][dn][u * 4 + j];
                    *reinterpret_cast<f32x4*>(&red[rbase + c * 16 + u * 4]) = tmp;
                }
            }
        }
        __syncthreads();
        if (wk == 0) {
#pragma unroll
            for (int c = 0; c < 2; ++c) {
                int c2 = ps * 2 + c, qn = c2 / 3, dn = c2 % 3;
#pragma unroll
                for (int u = 0; u < 4; ++u) {
                    f32x4 tmp = *reinterpret_cast<const f32x4*>(&red[rbase + c * 16 + u * 4]);
#pragma unroll
                    for (int j = 0; j < 4; ++j) acc[qn][dn][u * 4 + j] += tmp[j];
                }
            }
        }
    }
    __syncthreads();
    if (wk == 1) {
#pragma unroll
        for (int qn = 0; qn < 2; ++qn)
#pragma unroll
            for (int u = 0; u < 4; ++u) {
                f32x4 tmp;
#pragma unroll
                for (int j = 0; j < 4; ++j) tmp[j] = acc_l[qn][u * 4 + j];
                *reinterpret_cast<f32x4*>(&red[rbase + qn * 16 + u * 4]) = tmp;
            }
    }
    __syncthreads();
    if (wk == 0) {
#pragma unroll
        for (int qn = 0; qn < 2; ++qn)
#pragma unroll
            for (int u = 0; u < 4; ++u) {
                f32x4 tmp = *reinterpret_cast<const f32x4*>(&red[rbase + qn * 16 + u * 4]);
#pragma unroll
                for (int j = 0; j < 4; ++j) acc_l[qn][u * 4 + j] += tmp[j];
            }
        // normalize + write attn_out[b][n][head*96+d] (bf16 scratch)
        const int b = bh >> 3, head = bh & 7;
#pragma unroll
        for (int qn = 0; qn < 2; ++qn) {
#pragma unroll
            for (int reg = 0; reg < 16; ++reg) {
                int qloc = (reg & 3) + 8 * (reg >> 2) + 4 * h;
                int n = q0 + wr * 64 + qn * 32 + qloc;
                float inv = 1.f / acc_l[qn][reg];
                int rowoff = (b * 4096 + n) * 768 + head * 96;
#pragma unroll
                for (int dn = 0; dn < 3; ++dn)
                    Og[rowoff + dn * 32 + l31] = f2bf(acc[qn][dn][reg] * inv);
            }
        }
    }
}

// ---------------- proj GEMM: [8192x768] x [768x768]^T -> FP32 out ----------------
__global__ __launch_bounds__(256) void proj_gemm(const unsigned short* __restrict__ A,
                                                 const unsigned short* __restrict__ W,
                                                 float* __restrict__ out) {
    __shared__ __align__(16) unsigned short As[128 * 40];
    __shared__ __align__(16) unsigned short Bs[128 * 40];
    const int t = threadIdx.x;
    const int w = t >> 6, l = t & 63;
    const int wm = (w >> 1) * 64, wn = (w & 1) * 64;
    const int lr = l & 15, lq = l >> 4;
    const int m0 = blockIdx.y * 128, n0 = blockIdx.x * 128;
    f32x4 acc[4][4] = {};
    for (int k0 = 0; k0 < 768; k0 += 32) {
        __syncthreads();
#pragma unroll
        for (int i = 0; i < 2; ++i) {
            int v = t + i * 256;
            int r = v >> 2, c8 = (v & 3) * 8;
            *reinterpret_cast<ushort8*>(&As[r * 40 + c8]) =
                *reinterpret_cast<const ushort8*>(&A[(m0 + r) * 768 + k0 + c8]);
            *reinterpret_cast<ushort8*>(&Bs[r * 40 + c8]) =
                *reinterpret_cast<const ushort8*>(&W[(n0 + r) * 768 + k0 + c8]);
        }
        __syncthreads();
        bf16x8 af[4], bfr[4];
#pragma unroll
        for (int mt = 0; mt < 4; ++mt)
            af[mt] = *reinterpret_cast<const bf16x8*>(&As[(wm + mt * 16 + lr) * 40 + lq * 8]);
#pragma unroll
        for (int nt = 0; nt < 4; ++nt)
            bfr[nt] = *reinterpret_cast<const bf16x8*>(&Bs[(wn + nt * 16 + lr) * 40 + lq * 8]);
#pragma unroll
        for (int mt = 0; mt < 4; ++mt)
#pragma unroll
            for (int nt = 0; nt < 4; ++nt)
                acc[mt][nt] = mfma16(af[mt], bfr[nt], acc[mt][nt]);
    }
#pragma unroll
    for (int nt = 0; nt < 4; ++nt) {
        int gn = n0 + wn + nt * 16 + lr;
#pragma unroll
        for (int mt = 0; mt < 4; ++mt) {
#pragma unroll
            for (int r = 0; r < 4; ++r) {
                int gm = m0 + wm + mt * 16 + lq * 4 + r;
                out[gm * 768 + gn] = acc[mt][nt][r];
            }
        }
    }
}

extern "C" void kernel_launch(void* const* d_in, const int* in_sizes, int n_in,
                              void* d_out, int out_size, void* d_ws, size_t ws_size,
                              hipStream_t stream) {
    const float* x     = (const float*)d_in[0];   // [2,4096,768] fp32
    const float* wqkv  = (const float*)d_in[1];   // [2304,768] fp32
    const float* wproj = (const float*)d_in[2];   // [768,768] fp32
    float* out = (float*)d_out;                   // fp32 [2,4096,768]
    char* ws = (char*)d_ws;
    unsigned short* xb     = (unsigned short*)(ws);             // 12582912
    unsigned short* wqkvb  = (unsigned short*)(ws + 12582912);  // 3538944
    unsigned short* wprojb = (unsigned short*)(ws + 16121856);  // 1179648
    unsigned short* Qg     = (unsigned short*)(ws + 17301504);  // [B,H,N,D]
    unsigned short* Kg     = (unsigned short*)(ws + 29884416);  // [B,H,N,D] (rows kperm'd)
    unsigned short* Vtg    = (unsigned short*)(ws + 42467328);  // [B,H,D,N] identity
    unsigned short* attnb  = xb;                                // reuse: [B,N,C] bf16

    cvt3_f32_bf16<<<8448, 256, 0, stream>>>(x, wqkv, wproj, xb, wqkvb, wprojb);
    qkv_gemm<<<dim3(18, 64), 256, 0, stream>>>(xb, wqkvb, Qg, Kg, Vtg);
    attn_kernel<<<dim3(32, 16), 256, 0, stream>>>(Qg, Kg, Vtg, attnb);
    proj_gemm<<<dim3(6, 64), 256, 0, stream>>>(attnb, wprojb, out);
}

// Round 8
// 300.624 us; speedup vs baseline: 1.2322x; 1.2322x over previous
//
#include <hip/hip_runtime.h>

typedef __bf16 bf16;
typedef __attribute__((ext_vector_type(8))) __bf16 bf16x8;
typedef __attribute__((ext_vector_type(2))) __bf16 bf16x2;
typedef __attribute__((ext_vector_type(4))) float f32x4;
typedef __attribute__((ext_vector_type(16))) float f32x16;
typedef __attribute__((ext_vector_type(8))) unsigned short ushort8;   // 16B
typedef __attribute__((ext_vector_type(4))) unsigned short ushort4v;  // 8B

__device__ __forceinline__ unsigned short f2bf(float f) {
    union { float f; unsigned int u; } v; v.f = f;
    unsigned int u = v.u;
    return (unsigned short)((u + 0x7fffu + ((u >> 16) & 1u)) >> 16);
}

#if __has_builtin(__builtin_amdgcn_cvt_pk_bf16_f32)
__device__ __forceinline__ unsigned int pk2bf(float a, float b) {
    union { bf16x2 v; unsigned int u; } c;
    c.v = __builtin_amdgcn_cvt_pk_bf16_f32(a, b);
    return c.u;
}
#else
__device__ __forceinline__ unsigned int pk2bf(float a, float b) {
    return (unsigned int)f2bf(a) | ((unsigned int)f2bf(b) << 16);
}
#endif

__device__ __forceinline__ f32x4 mfma16(bf16x8 a, bf16x8 b, f32x4 c) {
    return __builtin_amdgcn_mfma_f32_16x16x32_bf16(a, b, c, 0, 0, 0);
}
__device__ __forceinline__ f32x16 mfma32(bf16x8 a, bf16x8 b, f32x16 c) {
    return __builtin_amdgcn_mfma_f32_32x32x16_bf16(a, b, c, 0, 0, 0);
}

// ---------------- fused fp32 -> bf16 convert ----------------
__global__ void cvt3_f32_bf16(const float* __restrict__ x, const float* __restrict__ wq,
                              const float* __restrict__ wp,
                              unsigned short* __restrict__ xb, unsigned short* __restrict__ wqb,
                              unsigned short* __restrict__ wpb) {
    int i = blockIdx.x * 256 + threadIdx.x;   // float4 index
    const float* in; unsigned short* out; int base;
    if (i < 1572864)      { in = x;  out = xb;  base = i; }
    else if (i < 2015232) { in = wq; out = wqb; base = i - 1572864; }
    else if (i < 2162688) { in = wp; out = wpb; base = i - 2015232; }
    else return;
    float4 f = reinterpret_cast<const float4*>(in)[base];
    union { ushort4v v; unsigned int u[2]; } o;
    o.u[0] = pk2bf(f.x, f.y);
    o.u[1] = pk2bf(f.z, f.w);
    reinterpret_cast<ushort4v*>(out)[base] = o.v;
}

// key permutation for 32x32 S^T C-layout -> PV A-layout:  p: a -> bits (a0,a1,a3,a4,a2)
__device__ __forceinline__ int kperm(int k5) {
    return (k5 & 3) | (((k5 >> 3) & 1) << 2) | (((k5 >> 4) & 1) << 3) | (((k5 >> 2) & 1) << 4);
}

// ---------------- QKV GEMM -> fragment-ready chunked layouts ----------------
// Qf/Kf/Vf are arrays of 1KB chunks (512 ushorts); lane l of a wave reads ushort index l*8.
// Qf chunk (bh, qg, kq):      lane h*32+l31 holds Q[qg*32+l31][kq*16+h*8 .. +7]   (Q scaled)
// Kf chunk (bh, kg, kq):      lane h*32+p   holds K[kg*32+n5][kq*16+h*8 .. +7], p=kperm(n5)
// Vf chunk (bh, kg, dn*2+f):  lane hh*32+dl holds V[key=kg*32+f*16+hh*8+j][d=dn*32+dl]
__global__ __launch_bounds__(256) void qkv_gemm(const unsigned short* __restrict__ A,
                                                const unsigned short* __restrict__ W,
                                                unsigned short* __restrict__ Qf,
                                                unsigned short* __restrict__ Kf,
                                                unsigned short* __restrict__ Vf) {
    __shared__ __align__(16) unsigned short As[128 * 40];
    __shared__ __align__(16) unsigned short Bs[128 * 40];
    const int t = threadIdx.x;
    const int w = t >> 6, l = t & 63;
    const int wm = (w >> 1) * 64, wn = (w & 1) * 64;
    const int lr = l & 15, lq = l >> 4;
    const int m0 = blockIdx.y * 128, n0 = blockIdx.x * 128;
    f32x4 acc[4][4] = {};
    for (int k0 = 0; k0 < 768; k0 += 32) {
        __syncthreads();
#pragma unroll
        for (int i = 0; i < 2; ++i) {
            int v = t + i * 256;
            int r = v >> 2, c8 = (v & 3) * 8;
            *reinterpret_cast<ushort8*>(&As[r * 40 + c8]) =
                *reinterpret_cast<const ushort8*>(&A[(m0 + r) * 768 + k0 + c8]);
            *reinterpret_cast<ushort8*>(&Bs[r * 40 + c8]) =
                *reinterpret_cast<const ushort8*>(&W[(n0 + r) * 768 + k0 + c8]);
        }
        __syncthreads();
        bf16x8 af[4], bfr[4];
#pragma unroll
        for (int mt = 0; mt < 4; ++mt)
            af[mt] = *reinterpret_cast<const bf16x8*>(&As[(wm + mt * 16 + lr) * 40 + lq * 8]);
#pragma unroll
        for (int nt = 0; nt < 4; ++nt)
            bfr[nt] = *reinterpret_cast<const bf16x8*>(&Bs[(wn + nt * 16 + lr) * 40 + lq * 8]);
#pragma unroll
        for (int mt = 0; mt < 4; ++mt)
#pragma unroll
            for (int nt = 0; nt < 4; ++nt)
                acc[mt][nt] = mfma16(af[mt], bfr[nt], acc[mt][nt]);
    }
#pragma unroll
    for (int nt = 0; nt < 4; ++nt) {
        int gn = n0 + wn + nt * 16 + lr;
        int tsel = gn / 768, rem = gn - tsel * 768;
        int hh8 = rem / 96, d = rem - hh8 * 96;
#pragma unroll
        for (int mt = 0; mt < 4; ++mt) {
#pragma unroll
            for (int r = 0; r < 4; ++r) {
                int gm = m0 + wm + mt * 16 + lq * 4 + r;
                int b = gm >> 12, n = gm & 4095;
                int bh = b * 8 + hh8;
                float val = acc[mt][nt][r];
                if (tsel == 0) {
                    int qg = n >> 5, l31 = n & 31;
                    int kq = d >> 4, h2 = (d >> 3) & 1, j = d & 7;
                    Qf[((((bh * 128 + qg) * 6 + kq)) << 9) + ((h2 * 32 + l31) << 3) + j] =
                        f2bf(val * 0.14724444f);
                } else if (tsel == 1) {
                    int kg = n >> 5, p5 = kperm(n & 31);
                    int kq = d >> 4, h2 = (d >> 3) & 1, j = d & 7;
                    Kf[((((bh * 128 + kg) * 6 + kq)) << 9) + ((h2 * 32 + p5) << 3) + j] =
                        f2bf(val);
                } else {
                    int kg = n >> 5, r5 = n & 31;
                    int f = r5 >> 4, hv = (r5 >> 3) & 1, j = r5 & 7;
                    int dn = d >> 5, dl = d & 31;
                    Vf[((((bh * 128 + kg) * 6 + dn * 2 + f)) << 9) + ((hv * 32 + dl) << 3) + j] =
                        f2bf(val);
                }
            }
        }
    }
}

// ---------------- Flash attention: barrier-free, direct-from-L2 fragments ----------------
// 256 thr = 4 waves: wr (64 q-rows), wk (kv half: keys wk*2048..+2047, 64 iters of 32).
// All operand loads are coalesced global b128 from fragment-ready chunks (SGPR base +
// constant lane offset). No LDS / no barriers in the loop; epilogue wk-reduce as R7.
// XCD swizzle: bh = (b&7)*2 + ((b>>3)>>5) pins each bh's K/V (1.6MB) to one XCD L2.
__global__ __launch_bounds__(256, 2) void attn_kernel(const unsigned short* __restrict__ Qf,
                                                      const unsigned short* __restrict__ Kf,
                                                      const unsigned short* __restrict__ Vf,
                                                      unsigned short* __restrict__ Og) {
    __shared__ __align__(16) float red[4608];   // 128 x 36 epilogue reduce
    const int t = threadIdx.x;
    const int w = t >> 6, l = t & 63;
    const int wr = w >> 1, wk = w & 1;
    const int l31 = l & 31, h = l >> 5;
    const int b0 = blockIdx.x;
    const int kk = b0 >> 3;
    const int bh = (b0 & 7) * 2 + (kk >> 5);
    const int q0 = (kk & 31) * 128;
    const int voff = l << 3;   // lane's ushort offset within a chunk

    // Q fragments: 12 coalesced b128 loads, loop-invariant
    bf16x8 aq[2][6];
#pragma unroll
    for (int qn = 0; qn < 2; ++qn) {
        long qb = ((long)((bh * 128 + (q0 >> 5) + wr * 2 + qn) * 6)) << 9;
#pragma unroll
        for (int kq = 0; kq < 6; ++kq)
            aq[qn][kq] = *reinterpret_cast<const bf16x8*>(&Qf[qb + (kq << 9) + voff]);
    }

    bf16x8 ones8;
#pragma unroll
    for (int i = 0; i < 8; ++i) ones8[i] = (__bf16)1.0f;

    f32x16 acc[2][3] = {};   // [qn][dn]
    f32x16 acc_l[2] = {};

    for (int it = 0; it < 64; ++it) {
        const int kt = wk * 64 + it;
        const long kbase = ((long)((bh * 128 + kt) * 6)) << 9;
        // S^T = K_perm Q^T (32x32x16)
        f32x16 s[2] = {};
#pragma unroll
        for (int kq = 0; kq < 6; ++kq) {
            bf16x8 bk = *reinterpret_cast<const bf16x8*>(&Kf[kbase + (kq << 9) + voff]);
            s[0] = mfma32(bk, aq[0][kq], s[0]);
            s[1] = mfma32(bk, aq[1][kq], s[1]);
        }
        // p = exp2(s); C-reg -> PV A-frag slot map: frag f slot j <- reg (j&3)+8*((j>>2)&1)+4*f
        union PF { unsigned int u[4]; bf16x8 v8; } p[2][2];
#pragma unroll
        for (int qn = 0; qn < 2; ++qn) {
            float e[16];
#pragma unroll
            for (int r = 0; r < 16; ++r) e[r] = __builtin_amdgcn_exp2f(s[qn][r]);
#pragma unroll
            for (int f = 0; f < 2; ++f) {
                p[qn][f].u[0] = pk2bf(e[4 * f + 0], e[4 * f + 1]);
                p[qn][f].u[1] = pk2bf(e[4 * f + 2], e[4 * f + 3]);
                p[qn][f].u[2] = pk2bf(e[8 + 4 * f + 0], e[8 + 4 * f + 1]);
                p[qn][f].u[3] = pk2bf(e[8 + 4 * f + 2], e[8 + 4 * f + 3]);
            }
        }
        // O += P V (32x32x16), V fragments straight from L2
#pragma unroll
        for (int dn = 0; dn < 3; ++dn) {
#pragma unroll
            for (int f = 0; f < 2; ++f) {
                bf16x8 vb = *reinterpret_cast<const bf16x8*>(
                    &Vf[kbase + ((dn * 2 + f) << 9) + voff]);
                acc[0][dn] = mfma32(p[0][f].v8, vb, acc[0][dn]);
                acc[1][dn] = mfma32(p[1][f].v8, vb, acc[1][dn]);
            }
        }
#pragma unroll
        for (int qn = 0; qn < 2; ++qn)
#pragma unroll
            for (int f = 0; f < 2; ++f)
                acc_l[qn] = mfma32(p[qn][f].v8, ones8, acc_l[qn]);
    }

    // ---- cross-wave reduce over wk (pairs, stride 36 floats) ----
    const int rbase = (wr * 64 + l) * 36;
#pragma unroll
    for (int ps = 0; ps < 3; ++ps) {
        __syncthreads();
        if (wk == 1) {
#pragma unroll
            for (int c = 0; c < 2; ++c) {
                int c2 = ps * 2 + c, qn = c2 / 3, dn = c2 % 3;
#pragma unroll
                for (int u = 0; u < 4; ++u) {
                    f32x4 tmp;
#pragma unroll
                    for (int j = 0; j < 4; ++j) tmp[j] = acc[qn][dn][u * 4 + j];
                    *reinterpret_cast<f32x4*>(&red[rbase + c * 16 + u * 4]) = tmp;
                }
            }
        }
        __syncthreads();
        if (wk == 0) {
#pragma unroll
            for (int c = 0; c < 2; ++c) {
                int c2 = ps * 2 + c, qn = c2 / 3, dn = c2 % 3;
#pragma unroll
                for (int u = 0; u < 4; ++u) {
                    f32x4 tmp = *reinterpret_cast<const f32x4*>(&red[rbase + c * 16 + u * 4]);
#pragma unroll
                    for (int j = 0; j < 4; ++j) acc[qn][dn][u * 4 + j] += tmp[j];
                }
            }
        }
    }
    __syncthreads();
    if (wk == 1) {
#pragma unroll
        for (int qn = 0; qn < 2; ++qn)
#pragma unroll
            for (int u = 0; u < 4; ++u) {
                f32x4 tmp;
#pragma unroll
                for (int j = 0; j < 4; ++j) tmp[j] = acc_l[qn][u * 4 + j];
                *reinterpret_cast<f32x4*>(&red[rbase + qn * 16 + u * 4]) = tmp;
            }
    }
    __syncthreads();
    if (wk == 0) {
#pragma unroll
        for (int qn = 0; qn < 2; ++qn)
#pragma unroll
            for (int u = 0; u < 4; ++u) {
                f32x4 tmp = *reinterpret_cast<const f32x4*>(&red[rbase + qn * 16 + u * 4]);
#pragma unroll
                for (int j = 0; j < 4; ++j) acc_l[qn][u * 4 + j] += tmp[j];
            }
        // normalize + write attn_out[b][n][head*96+d] (bf16 scratch)
        const int b = bh >> 3, head = bh & 7;
#pragma unroll
        for (int qn = 0; qn < 2; ++qn) {
#pragma unroll
            for (int reg = 0; reg < 16; ++reg) {
                int qloc = (reg & 3) + 8 * (reg >> 2) + 4 * h;
                int n = q0 + wr * 64 + qn * 32 + qloc;
                float inv = 1.f / acc_l[qn][reg];
                int rowoff = (b * 4096 + n) * 768 + head * 96;
#pragma unroll
                for (int dn = 0; dn < 3; ++dn)
                    Og[rowoff + dn * 32 + l31] = f2bf(acc[qn][dn][reg] * inv);
            }
        }
    }
}

// ---------------- proj GEMM: [8192x768] x [768x768]^T -> FP32 out ----------------
__global__ __launch_bounds__(256) void proj_gemm(const unsigned short* __restrict__ A,
                                                 const unsigned short* __restrict__ W,
                                                 float* __restrict__ out) {
    __shared__ __align__(16) unsigned short As[128 * 40];
    __shared__ __align__(16) unsigned short Bs[128 * 40];
    const int t = threadIdx.x;
    const int w = t >> 6, l = t & 63;
    const int wm = (w >> 1) * 64, wn = (w & 1) * 64;
    const int lr = l & 15, lq = l >> 4;
    const int m0 = blockIdx.y * 128, n0 = blockIdx.x * 128;
    f32x4 acc[4][4] = {};
    for (int k0 = 0; k0 < 768; k0 += 32) {
        __syncthreads();
#pragma unroll
        for (int i = 0; i < 2; ++i) {
            int v = t + i * 256;
            int r = v >> 2, c8 = (v & 3) * 8;
            *reinterpret_cast<ushort8*>(&As[r * 40 + c8]) =
                *reinterpret_cast<const ushort8*>(&A[(m0 + r) * 768 + k0 + c8]);
            *reinterpret_cast<ushort8*>(&Bs[r * 40 + c8]) =
                *reinterpret_cast<const ushort8*>(&W[(n0 + r) * 768 + k0 + c8]);
        }
        __syncthreads();
        bf16x8 af[4], bfr[4];
#pragma unroll
        for (int mt = 0; mt < 4; ++mt)
            af[mt] = *reinterpret_cast<const bf16x8*>(&As[(wm + mt * 16 + lr) * 40 + lq * 8]);
#pragma unroll
        for (int nt = 0; nt < 4; ++nt)
            bfr[nt] = *reinterpret_cast<const bf16x8*>(&Bs[(wn + nt * 16 + lr) * 40 + lq * 8]);
#pragma unroll
        for (int mt = 0; mt < 4; ++mt)
#pragma unroll
            for (int nt = 0; nt < 4; ++nt)
                acc[mt][nt] = mfma16(af[mt], bfr[nt], acc[mt][nt]);
    }
#pragma unroll
    for (int nt = 0; nt < 4; ++nt) {
        int gn = n0 + wn + nt * 16 + lr;
#pragma unroll
        for (int mt = 0; mt < 4; ++mt) {
#pragma unroll
            for (int r = 0; r < 4; ++r) {
                int gm = m0 + wm + mt * 16 + lq * 4 + r;
                out[gm * 768 + gn] = acc[mt][nt][r];
            }
        }
    }
}

extern "C" void kernel_launch(void* const* d_in, const int* in_sizes, int n_in,
                              void* d_out, int out_size, void* d_ws, size_t ws_size,
                              hipStream_t stream) {
    const float* x     = (const float*)d_in[0];   // [2,4096,768] fp32
    const float* wqkv  = (const float*)d_in[1];   // [2304,768] fp32
    const float* wproj = (const float*)d_in[2];   // [768,768] fp32
    float* out = (float*)d_out;                   // fp32 [2,4096,768]
    char* ws = (char*)d_ws;
    unsigned short* xb     = (unsigned short*)(ws);             // 12582912
    unsigned short* wqkvb  = (unsigned short*)(ws + 12582912);  // 3538944
    unsigned short* wprojb = (unsigned short*)(ws + 16121856);  // 1179648
    unsigned short* Qf     = (unsigned short*)(ws + 17301504);  // 12.58MB frag chunks
    unsigned short* Kf     = (unsigned short*)(ws + 29884416);  // 12.58MB frag chunks
    unsigned short* Vf     = (unsigned short*)(ws + 42467328);  // 12.58MB frag chunks
    unsigned short* attnb  = xb;                                // reuse: [B,N,C] bf16

    cvt3_f32_bf16<<<8448, 256, 0, stream>>>(x, wqkv, wproj, xb, wqkvb, wprojb);
    qkv_gemm<<<dim3(18, 64), 256, 0, stream>>>(xb, wqkvb, Qf, Kf, Vf);
    attn_kernel<<<512, 256, 0, stream>>>(Qf, Kf, Vf, attnb);
    proj_gemm<<<dim3(6, 64), 256, 0, stream>>>(attnb, wprojb, out);
}